// Round 1
// baseline (1454.474 us; speedup 1.0000x reference)
//
#include <hip/hip_runtime.h>
#include <stdint.h>

typedef unsigned short u16;

#define S_   7
#define B_   4096
#define D_   1024
#define E_   128
#define H_   512
#define V_   200
#define D0_  1152   // D+E
#define KX0  1664   // D0+H  (xcat width: [x | h0])
#define KX1  1024   // 2H    (x1cat width: [x1 | h1])
#define G4H  2048   // 4H

typedef __bf16 bf16x8 __attribute__((ext_vector_type(8)));
typedef float  f32x4  __attribute__((ext_vector_type(4)));

__device__ __forceinline__ u16 f2bf(float f) {
  union { float f; uint32_t u; } v; v.f = f;
  uint32_t r = v.u + 0x7fffu + ((v.u >> 16) & 1u);   // RNE
  return (u16)(r >> 16);
}
__device__ __forceinline__ float sigmoidf_(float x) { return 1.0f / (1.0f + __expf(-x)); }

// ---------------- weight convert / concat (f32 -> bf16), row = by, col = k ----
__global__ void pack_cat(const float* __restrict__ A, int ka,
                         const float* __restrict__ Bsrc, int kb,
                         u16* __restrict__ dst) {
  int k = blockIdx.x * 256 + threadIdx.x;
  long row = blockIdx.y;
  int kk = ka + kb;
  if (k >= kk) return;
  float v = (k < ka) ? A[row * ka + k] : Bsrc[row * kb + (k - ka)];
  dst[row * kk + k] = f2bf(v);
}

// ---------------- init xcat: pred part bf16, rest zero -----------------------
__global__ void init_xcat(const float* __restrict__ pred, u16* __restrict__ xcat) {
  int k = blockIdx.x * 256 + threadIdx.x;
  long b = blockIdx.y;
  if (k >= KX0) return;
  u16 v = 0;
  if (k < D_) v = f2bf(pred[b * D_ + k]);
  xcat[b * KX0 + k] = v;
}

__global__ void zero_f(float* __restrict__ p, int n) {
  for (int i = blockIdx.x * 256 + threadIdx.x; i < n; i += gridDim.x * 256) p[i] = 0.f;
}
__global__ void zero_u16k(u16* __restrict__ p, int n) {
  for (int i = blockIdx.x * 256 + threadIdx.x; i < n; i += gridDim.x * 256) p[i] = 0;
}

// ---------------- per-slot embedding gather into xcat[:,1024:1152] -----------
__global__ void gather_emb(const float* __restrict__ emb_s, const int* __restrict__ idx_s,
                           u16* __restrict__ xcat) {
  long b = blockIdx.x;
  int e = threadIdx.x;
  int ix = idx_s[b];
  xcat[b * KX0 + D_ + e] = f2bf(emb_s[(long)ix * E_ + e]);
}

// ---------------- bf16 MFMA GEMM: C[M,N] = A[M,K] @ W[N,K]^T -----------------
// 128x128 tile, BK=32, 256 threads = 4 waves (2x2 of 64x64), 16x16x32 MFMA.
__global__ __launch_bounds__(256)
void gemm_bt(const u16* __restrict__ A, int lda,
             const u16* __restrict__ W, int ldw,
             float* __restrict__ C, int ldc,
             int K, int ntn) {
  __shared__ __align__(16) u16 lA[128 * 32];
  __shared__ __align__(16) u16 lW[128 * 32];
  const int tid  = threadIdx.x;
  const int lane = tid & 63;
  const int wave = tid >> 6;
  const int tn = blockIdx.x % ntn;
  const int tm = blockIdx.x / ntn;
  const long row0 = (long)tm * 128;
  const long col0 = (long)tn * 128;
  const int wm = (wave >> 1) * 64;
  const int wn = (wave & 1) * 64;
  const int r_ = (tid * 8) >> 5;   // 0..63 (staging row)
  const int c_ = (tid * 8) & 31;   // staging col (8-elem group)
  const int fr = lane & 15;
  const int fk = (lane >> 4) * 8;

  f32x4 acc[4][4] = {};

  for (int k0 = 0; k0 < K; k0 += 32) {
    __syncthreads();
    // stage A tile (128x32) and W tile (128x32), 16B per thread per issue
    {
      const u16* g0 = A + (row0 + r_) * lda + k0 + c_;
      const u16* g1 = A + (row0 + 64 + r_) * lda + k0 + c_;
      *(uint4*)&lA[tid * 8]        = *(const uint4*)g0;
      *(uint4*)&lA[2048 + tid * 8] = *(const uint4*)g1;
      const u16* w0 = W + (col0 + r_) * ldw + k0 + c_;
      const u16* w1 = W + (col0 + 64 + r_) * ldw + k0 + c_;
      *(uint4*)&lW[tid * 8]        = *(const uint4*)w0;
      *(uint4*)&lW[2048 + tid * 8] = *(const uint4*)w1;
    }
    __syncthreads();
    bf16x8 af[4], wf[4];
    #pragma unroll
    for (int m = 0; m < 4; ++m)
      af[m] = *(const bf16x8*)&lA[(wm + m * 16 + fr) * 32 + fk];
    #pragma unroll
    for (int n = 0; n < 4; ++n)
      wf[n] = *(const bf16x8*)&lW[(wn + n * 16 + fr) * 32 + fk];
    #pragma unroll
    for (int m = 0; m < 4; ++m)
      #pragma unroll
      for (int n = 0; n < 4; ++n)
        acc[m][n] = __builtin_amdgcn_mfma_f32_16x16x32_bf16(af[m], wf[n], acc[m][n], 0, 0, 0);
  }

  const int cr = (lane >> 4) * 4;
  #pragma unroll
  for (int m = 0; m < 4; ++m)
    #pragma unroll
    for (int n = 0; n < 4; ++n)
      #pragma unroll
      for (int r = 0; r < 4; ++r)
        C[(row0 + wm + m * 16 + cr + r) * ldc + col0 + wn + n * 16 + fr] = acc[m][n][r];
}

// ---------------- LSTM cell pointwise: gates -> h,c --------------------------
__global__ void lstm_cell(const float* __restrict__ gates,
                          const float* __restrict__ bih, const float* __restrict__ bhh,
                          float* __restrict__ c,
                          u16* __restrict__ hdst, int hld, int hoff,
                          float* __restrict__ hf32) {
  int i = blockIdx.x * 256 + threadIdx.x;   // 0 .. B*H-1
  int b = i >> 9;                           // /512
  int j = i & 511;
  const float* g = gates + (long)b * G4H;
  float gi = g[j]          + bih[j]          + bhh[j];
  float gf = g[512 + j]    + bih[512 + j]    + bhh[512 + j];
  float gg = g[1024 + j]   + bih[1024 + j]   + bhh[1024 + j];
  float go = g[1536 + j]   + bih[1536 + j]   + bhh[1536 + j];
  float cv = c[i];
  float cn = sigmoidf_(gf) * cv + sigmoidf_(gi) * tanhf(gg);
  float hn = sigmoidf_(go) * tanhf(cn);
  c[i] = cn;
  hdst[(long)b * hld + hoff + j] = f2bf(hn);
  hf32[i] = hn;
}

// ---------------- highway combine: x1 = g*h0n + (1-g)*xlin -------------------
__global__ void highway_combine(const float* __restrict__ hwg, const float* __restrict__ hwb,
                                const float* __restrict__ h0f, const float* __restrict__ xlin,
                                u16* __restrict__ x1cat) {
  int i = blockIdx.x * 256 + threadIdx.x;
  int b = i >> 9;
  int j = i & 511;
  float gv = sigmoidf_(hwg[i] + hwb[j]);
  float x1 = gv * h0f[i] + (1.f - gv) * xlin[i];
  x1cat[(long)b * KX1 + j] = f2bf(x1);
}

extern "C" void kernel_launch(void* const* d_in, const int* in_sizes, int n_in,
                              void* d_out, int out_size, void* d_ws, size_t ws_size,
                              hipStream_t stream) {
  const float* pred   = (const float*)d_in[0];
  const int*   labels = (const int*)d_in[1];
  const float* emb    = (const float*)d_in[2];
  const float* Wih0   = (const float*)d_in[3];
  const float* Whh0   = (const float*)d_in[4];
  const float* bih0   = (const float*)d_in[5];
  const float* bhh0   = (const float*)d_in[6];
  const float* hwW0   = (const float*)d_in[7];
  const float* hwb0   = (const float*)d_in[8];
  const float* linW0  = (const float*)d_in[9];
  const float* Wih1   = (const float*)d_in[10];
  const float* Whh1   = (const float*)d_in[11];
  const float* bih1   = (const float*)d_in[12];
  const float* bhh1   = (const float*)d_in[13];
  float* out = (float*)d_out;

  char* ws = (char*)d_ws;
  size_t off = 0;
  auto alloc = [&](size_t bytes) {
    char* p = ws + off;
    off = (off + bytes + 255) & ~(size_t)255;
    return p;
  };
  u16* WC0   = (u16*)alloc((size_t)S_ * G4H * KX0 * 2);   // [Wih0|Whh0] bf16
  u16* HW0   = (u16*)alloc((size_t)S_ * H_  * KX0 * 2);   // hwW0 bf16
  u16* LN0   = (u16*)alloc((size_t)S_ * H_  * D0_ * 2);   // linW0 bf16
  u16* WC1   = (u16*)alloc((size_t)S_ * G4H * KX1 * 2);   // [Wih1|Whh1] bf16
  u16* xcat  = (u16*)alloc((size_t)B_ * KX0 * 2);         // [pred|emb|h0] bf16
  u16* x1cat = (u16*)alloc((size_t)B_ * KX1 * 2);         // [x1|h1] bf16
  float* gates = (float*)alloc((size_t)B_ * G4H * 4);
  float* c0    = (float*)alloc((size_t)B_ * H_ * 4);
  float* c1    = (float*)alloc((size_t)B_ * H_ * 4);
  float* h0f   = (float*)alloc((size_t)B_ * H_ * 4);
  // hwg/xlin alias gates: consumed (by combine) before gates is rewritten (gates1 GEMM)
  float* hwg  = gates;
  float* xlin = gates + (size_t)B_ * H_;

  // -------- phase A: weight conversion + state init (per-launch, deterministic)
  pack_cat<<<dim3(7, S_ * G4H), 256, 0, stream>>>(Wih0, D0_, Whh0, H_, WC0);
  pack_cat<<<dim3(7, S_ * H_),  256, 0, stream>>>(hwW0, KX0, hwW0, 0, HW0);
  pack_cat<<<dim3(5, S_ * H_),  256, 0, stream>>>(linW0, D0_, linW0, 0, LN0);
  pack_cat<<<dim3(4, S_ * G4H), 256, 0, stream>>>(Wih1, H_, Whh1, H_, WC1);
  init_xcat<<<dim3(7, B_), 256, 0, stream>>>(pred, xcat);
  zero_f<<<1024, 256, 0, stream>>>(c0, B_ * H_);
  zero_f<<<1024, 256, 0, stream>>>(c1, B_ * H_);
  zero_u16k<<<1024, 256, 0, stream>>>(x1cat, B_ * KX1);

  // -------- sequential slot loop
  for (int s = 0; s < S_; ++s) {
    gather_emb<<<B_, E_, 0, stream>>>(emb + (size_t)s * V_ * E_, labels + (size_t)s * B_, xcat);

    // layer-0 gates: [x|h0] @ [Wih0|Whh0]^T   (M=4096,N=2048,K=1664)
    gemm_bt<<<(B_ / 128) * (G4H / 128), 256, 0, stream>>>(
        xcat, KX0, WC0 + (size_t)s * G4H * KX0, KX0, gates, G4H, KX0, G4H / 128);
    lstm_cell<<<(B_ * H_) / 256, 256, 0, stream>>>(
        gates, bih0 + (size_t)s * G4H, bhh0 + (size_t)s * G4H, c0, xcat, KX0, D0_, h0f);

    // highway gate: [x|h0n] @ hwW0^T          (N=512,K=1664)
    gemm_bt<<<(B_ / 128) * (H_ / 128), 256, 0, stream>>>(
        xcat, KX0, HW0 + (size_t)s * H_ * KX0, KX0, hwg, H_, KX0, H_ / 128);
    // linear skip: x @ linW0^T                (N=512,K=1152; same A, K-cropped)
    gemm_bt<<<(B_ / 128) * (H_ / 128), 256, 0, stream>>>(
        xcat, KX0, LN0 + (size_t)s * H_ * D0_, D0_, xlin, H_, D0_, H_ / 128);
    highway_combine<<<(B_ * H_) / 256, 256, 0, stream>>>(hwg, hwb0 + (size_t)s * H_, h0f, xlin, x1cat);

    // layer-1 gates: [x1|h1] @ [Wih1|Whh1]^T  (M=4096,N=2048,K=1024)
    gemm_bt<<<(B_ / 128) * (G4H / 128), 256, 0, stream>>>(
        x1cat, KX1, WC1 + (size_t)s * G4H * KX1, KX1, gates, G4H, KX1, G4H / 128);
    lstm_cell<<<(B_ * H_) / 256, 256, 0, stream>>>(
        gates, bih1 + (size_t)s * G4H, bhh1 + (size_t)s * G4H, c1, x1cat, KX1, H_, out);
  }
}

// Round 2
// 1220.234 us; speedup vs baseline: 1.1920x; 1.1920x over previous
//
#include <hip/hip_runtime.h>
#include <stdint.h>

typedef unsigned short u16;

#define S_   7
#define B_   4096
#define D_   1024
#define E_   128
#define H_   512
#define V_   200
#define D0_  1152   // D+E
#define KX0  1664   // D0+H  (xcat width: [x | h0])
#define KX1  1024   // 2H    (x1cat width: [x1 | h1])
#define G4H  2048   // 4H

typedef __bf16 bf16x8 __attribute__((ext_vector_type(8)));
typedef float  f32x4  __attribute__((ext_vector_type(4)));
typedef u16    u16x8  __attribute__((ext_vector_type(8)));

__device__ __forceinline__ u16 f2bf(float f) {
  union { float f; uint32_t u; } v; v.f = f;
  uint32_t r = v.u + 0x7fffu + ((v.u >> 16) & 1u);   // RNE
  return (u16)(r >> 16);
}
__device__ __forceinline__ float sigmoidf_(float x) { return 1.0f / (1.0f + __expf(-x)); }

__device__ __forceinline__ void glds16(const u16* g, u16* l) {
  __builtin_amdgcn_global_load_lds(
      (const __attribute__((address_space(1))) uint32_t*)g,
      (__attribute__((address_space(3))) uint32_t*)l, 16, 0, 0);
}

// ---------- vectorized f32->bf16 pack with row remap + zero pad --------------
// dst[drow][k8..k8+8) : k8<ka from A (stride ka), ka<=k8<ka+kb from B (stride kb),
// else 0.  drow = (row>>sh)*rpd + roff + (row & ((1<<sh)-1)).  ka,kb multiples of 8.
__global__ void pack8(const float* __restrict__ A, int ka,
                      const float* __restrict__ Bsrc, int kb,
                      u16* __restrict__ dst, int kk,
                      int sh, int rpd, int roff) {
  int k8 = (blockIdx.x * 256 + threadIdx.x) * 8;
  long row = blockIdx.y;
  if (k8 >= kk) return;
  long drow = (row >> sh) * (long)rpd + roff + (row & ((1L << sh) - 1));
  float v[8];
  if (k8 + 8 <= ka) {
    const float4* p = (const float4*)(A + row * ka + k8);
    float4 x = p[0], y = p[1];
    v[0]=x.x; v[1]=x.y; v[2]=x.z; v[3]=x.w; v[4]=y.x; v[5]=y.y; v[6]=y.z; v[7]=y.w;
  } else if (k8 + 8 <= ka + kb) {
    const float4* p = (const float4*)(Bsrc + row * kb + (k8 - ka));
    float4 x = p[0], y = p[1];
    v[0]=x.x; v[1]=x.y; v[2]=x.z; v[3]=x.w; v[4]=y.x; v[5]=y.y; v[6]=y.z; v[7]=y.w;
  } else {
    #pragma unroll
    for (int j = 0; j < 8; ++j) v[j] = 0.f;
  }
  u16x8 o;
  #pragma unroll
  for (int j = 0; j < 8; ++j) o[j] = f2bf(v[j]);
  *(u16x8*)&dst[drow * kk + k8] = o;
}

__global__ void zero_f(float* __restrict__ p, int n) {
  for (int i = blockIdx.x * 256 + threadIdx.x; i < n; i += gridDim.x * 256) p[i] = 0.f;
}
__global__ void zero_u16k(u16* __restrict__ p, int n) {
  for (int i = blockIdx.x * 256 + threadIdx.x; i < n; i += gridDim.x * 256) p[i] = 0;
}

// ---------------- per-slot embedding gather into xcat[:,1024:1152] -----------
__global__ void gather_emb(const float* __restrict__ emb_s, const int* __restrict__ idx_s,
                           u16* __restrict__ xcat) {
  long b = blockIdx.x;
  int e = threadIdx.x;
  int ix = idx_s[b];
  xcat[b * KX0 + D_ + e] = f2bf(emb_s[(long)ix * E_ + e]);
}

// ---------------- bf16 MFMA GEMM: C[M,N] = A[M,K] @ W[N,K]^T -----------------
// 128x128 tile, BK=32, 4 waves (2x2 of 64x64), 16x16x32 MFMA,
// global_load_lds width-16 staging (m97 structure).
__global__ __launch_bounds__(256)
void gemm_bt(const u16* __restrict__ A, int lda,
             const u16* __restrict__ W, int ldw,
             float* __restrict__ C, int ldc,
             int K, int ntn) {
  __shared__ __align__(16) u16 lA[128 * 32];
  __shared__ __align__(16) u16 lW[128 * 32];
  const int tid  = threadIdx.x;
  const int lane = tid & 63;
  const int wave = tid >> 6;
  const int tn = blockIdx.x % ntn;
  const int tm = blockIdx.x / ntn;
  const long row0 = (long)tm * 128;
  const long col0 = (long)tn * 128;
  const int wm = (wave >> 1) * 64;
  const int wn = (wave & 1) * 64;
  const int fr = lane & 15;
  const int fk = (lane >> 4) * 8;
  // staging: wave w covers rows [w*32, w*32+32) of each 128x32 tile, 2 issues
  const int srow = lane >> 2;          // 0..15
  const int scol = (lane & 3) * 8;
  const int wr   = wave * 32;

  const u16* ga = A + (row0 + wr + srow) * lda + scol;
  const u16* gw = W + (col0 + wr + srow) * ldw + scol;
  u16* la0 = &lA[wr * 32];
  u16* lw0 = &lW[wr * 32];

  f32x4 acc[4][4] = {};

  for (int k0 = 0; k0 < K; k0 += 32) {
    __syncthreads();
    glds16(ga + k0,            la0);
    glds16(ga + k0 + 16 * lda, la0 + 16 * 32);
    glds16(gw + k0,            lw0);
    glds16(gw + k0 + 16 * ldw, lw0 + 16 * 32);
    __syncthreads();
    bf16x8 af[4], wf[4];
    #pragma unroll
    for (int m = 0; m < 4; ++m)
      af[m] = *(const bf16x8*)&lA[(wm + m * 16 + fr) * 32 + fk];
    #pragma unroll
    for (int n = 0; n < 4; ++n)
      wf[n] = *(const bf16x8*)&lW[(wn + n * 16 + fr) * 32 + fk];
    #pragma unroll
    for (int m = 0; m < 4; ++m)
      #pragma unroll
      for (int n = 0; n < 4; ++n)
        acc[m][n] = __builtin_amdgcn_mfma_f32_16x16x32_bf16(af[m], wf[n], acc[m][n], 0, 0, 0);
  }

  const int cr = (lane >> 4) * 4;
  #pragma unroll
  for (int m = 0; m < 4; ++m)
    #pragma unroll
    for (int n = 0; n < 4; ++n)
      #pragma unroll
      for (int r = 0; r < 4; ++r)
        C[(row0 + wm + m * 16 + cr + r) * ldc + col0 + wn + n * 16 + fr] = acc[m][n][r];
}

// ---------------- LSTM cell pointwise: gates -> h,c --------------------------
__global__ void lstm_cell(const float* __restrict__ gates,
                          const float* __restrict__ bih, const float* __restrict__ bhh,
                          float* __restrict__ c,
                          u16* __restrict__ hdst, int hld, int hoff,
                          float* __restrict__ hf32) {
  int i = blockIdx.x * 256 + threadIdx.x;   // 0 .. B*H-1
  int b = i >> 9;                           // /512
  int j = i & 511;
  const float* g = gates + (long)b * G4H;
  float gi = g[j]          + bih[j]          + bhh[j];
  float gf = g[512 + j]    + bih[512 + j]    + bhh[512 + j];
  float gg = g[1024 + j]   + bih[1024 + j]   + bhh[1024 + j];
  float go = g[1536 + j]   + bih[1536 + j]   + bhh[1536 + j];
  float cv = c[i];
  float cn = sigmoidf_(gf) * cv + sigmoidf_(gi) * tanhf(gg);
  float hn = sigmoidf_(go) * tanhf(cn);
  c[i] = cn;
  hdst[(long)b * hld + hoff + j] = f2bf(hn);
  hf32[i] = hn;
}

// ---------------- highway combine: x1 = g*h0n + (1-g)*xlin -------------------
// hl is [B,1024]: cols 0..511 = highway gate pre-act, 512..1023 = linear skip
__global__ void highway_combine(const float* __restrict__ hl, const float* __restrict__ hwb,
                                const float* __restrict__ h0f, u16* __restrict__ x1cat) {
  int i = blockIdx.x * 256 + threadIdx.x;
  int b = i >> 9;
  int j = i & 511;
  float gv = sigmoidf_(hl[(long)b * 1024 + j] + hwb[j]);
  float x1 = gv * h0f[i] + (1.f - gv) * hl[(long)b * 1024 + 512 + j];
  x1cat[(long)b * KX1 + j] = f2bf(x1);
}

extern "C" void kernel_launch(void* const* d_in, const int* in_sizes, int n_in,
                              void* d_out, int out_size, void* d_ws, size_t ws_size,
                              hipStream_t stream) {
  const float* pred   = (const float*)d_in[0];
  const int*   labels = (const int*)d_in[1];
  const float* emb    = (const float*)d_in[2];
  const float* Wih0   = (const float*)d_in[3];
  const float* Whh0   = (const float*)d_in[4];
  const float* bih0   = (const float*)d_in[5];
  const float* bhh0   = (const float*)d_in[6];
  const float* hwW0   = (const float*)d_in[7];
  const float* hwb0   = (const float*)d_in[8];
  const float* linW0  = (const float*)d_in[9];
  const float* Wih1   = (const float*)d_in[10];
  const float* Whh1   = (const float*)d_in[11];
  const float* bih1   = (const float*)d_in[12];
  const float* bhh1   = (const float*)d_in[13];
  float* out = (float*)d_out;

  char* ws = (char*)d_ws;
  size_t off = 0;
  auto alloc = [&](size_t bytes) {
    char* p = ws + off;
    off = (off + bytes + 255) & ~(size_t)255;
    return p;
  };
  u16* WC0   = (u16*)alloc((size_t)S_ * G4H * KX0 * 2);   // [Wih0|Whh0] bf16
  u16* WHL   = (u16*)alloc((size_t)S_ * 1024 * KX0 * 2);  // [hwW0 ; linW0(pad K=1664)]
  u16* WC1   = (u16*)alloc((size_t)S_ * G4H * KX1 * 2);   // [Wih1|Whh1] bf16
  u16* xcat  = (u16*)alloc((size_t)B_ * KX0 * 2);         // [pred|emb|h0] bf16
  u16* x1cat = (u16*)alloc((size_t)B_ * KX1 * 2);         // [x1|h1] bf16
  float* gates = (float*)alloc((size_t)B_ * G4H * 4);
  float* c0    = (float*)alloc((size_t)B_ * H_ * 4);
  float* c1    = (float*)alloc((size_t)B_ * H_ * 4);
  float* h0f   = (float*)alloc((size_t)B_ * H_ * 4);
  // hl (highway/linear GEMM out, [B,1024]) aliases gates: gates is consumed by
  // lstm_cell before the WHL GEMM writes, and rewritten only by gates1 GEMM after combine.
  float* hl = gates;

  // -------- phase A: weight conversion + state init (per-launch, deterministic)
  pack8<<<dim3(1, S_ * G4H), 256, 0, stream>>>(Wih0, D0_, Whh0, H_, WC0, KX0, 22, 0, 0);
  pack8<<<dim3(1, S_ * H_),  256, 0, stream>>>(hwW0, KX0, nullptr, 0, WHL, KX0, 9, 1024, 0);
  pack8<<<dim3(1, S_ * H_),  256, 0, stream>>>(linW0, D0_, nullptr, 0, WHL, KX0, 9, 1024, 512);
  pack8<<<dim3(1, S_ * G4H), 256, 0, stream>>>(Wih1, H_, Whh1, H_, WC1, KX1, 22, 0, 0);
  pack8<<<dim3(1, B_),       256, 0, stream>>>(pred, D_, nullptr, 0, xcat, KX0, 22, 0, 0);
  zero_f<<<1024, 256, 0, stream>>>(c0, B_ * H_);
  zero_f<<<1024, 256, 0, stream>>>(c1, B_ * H_);
  zero_u16k<<<1024, 256, 0, stream>>>(x1cat, B_ * KX1);

  // -------- sequential slot loop
  for (int s = 0; s < S_; ++s) {
    gather_emb<<<B_, E_, 0, stream>>>(emb + (size_t)s * V_ * E_, labels + (size_t)s * B_, xcat);

    // layer-0 gates: [x|h0] @ [Wih0|Whh0]^T   (M=4096,N=2048,K=1664)
    gemm_bt<<<(B_ / 128) * (G4H / 128), 256, 0, stream>>>(
        xcat, KX0, WC0 + (size_t)s * G4H * KX0, KX0, gates, G4H, KX0, G4H / 128);
    lstm_cell<<<(B_ * H_) / 256, 256, 0, stream>>>(
        gates, bih0 + (size_t)s * G4H, bhh0 + (size_t)s * G4H, c0, xcat, KX0, D0_, h0f);

    // merged highway+linear: [x|h0n] @ [hwW0;linW0pad]^T  (N=1024,K=1664, 256 blocks)
    gemm_bt<<<(B_ / 128) * (1024 / 128), 256, 0, stream>>>(
        xcat, KX0, WHL + (size_t)s * 1024 * KX0, KX0, hl, 1024, KX0, 1024 / 128);
    highway_combine<<<(B_ * H_) / 256, 256, 0, stream>>>(hl, hwb0 + (size_t)s * H_, h0f, x1cat);

    // layer-1 gates: [x1|h1] @ [Wih1|Whh1]^T  (M=4096,N=2048,K=1024)
    gemm_bt<<<(B_ / 128) * (G4H / 128), 256, 0, stream>>>(
        x1cat, KX1, WC1 + (size_t)s * G4H * KX1, KX1, gates, G4H, KX1, G4H / 128);
    lstm_cell<<<(B_ * H_) / 256, 256, 0, stream>>>(
        gates, bih1 + (size_t)s * G4H, bhh1 + (size_t)s * G4H, c1, x1cat, KX1, H_, out);
  }
}

// Round 3
// 1046.109 us; speedup vs baseline: 1.3904x; 1.1665x over previous
//
#include <hip/hip_runtime.h>
#include <stdint.h>

typedef unsigned short u16;

#define S_   7
#define B_   4096
#define D_   1024
#define E_   128
#define H_   512
#define V_   200
#define D0_  1152   // D+E
#define KX0  1664   // D0+H  (xcat width: [x | h0])
#define KX1  1024   // 2H    (x1cat width: [x1 | h1])
#define G4H  2048   // 4H

typedef __bf16 bf16x8 __attribute__((ext_vector_type(8)));
typedef float  f32x4  __attribute__((ext_vector_type(4)));
typedef u16    u16x8  __attribute__((ext_vector_type(8)));

__device__ __forceinline__ u16 f2bf(float f) {
  union { float f; uint32_t u; } v; v.f = f;
  uint32_t r = v.u + 0x7fffu + ((v.u >> 16) & 1u);   // RNE
  return (u16)(r >> 16);
}
__device__ __forceinline__ float sigmoidf_(float x) { return 1.0f / (1.0f + __expf(-x)); }
__device__ __forceinline__ float tanhf_(float x) {
  float t = __expf(-2.f * fabsf(x));
  return copysignf((1.f - t) / (1.f + t), x);
}

__device__ __forceinline__ void glds16(const u16* g, u16* l) {
  __builtin_amdgcn_global_load_lds(
      (const __attribute__((address_space(1))) uint32_t*)g,
      (__attribute__((address_space(3))) uint32_t*)l, 16, 0, 0);
}

// ---------- vectorized f32->bf16 pack (identity rows, zero pad past ka) ------
__global__ void pack8(const float* __restrict__ A, int ka,
                      u16* __restrict__ dst, int kk) {
  int k8 = (blockIdx.x * 256 + threadIdx.x) * 8;
  long row = blockIdx.y;
  if (k8 >= kk) return;
  float v[8];
  if (k8 + 8 <= ka) {
    const float4* p = (const float4*)(A + row * ka + k8);
    float4 x = p[0], y = p[1];
    v[0]=x.x; v[1]=x.y; v[2]=x.z; v[3]=x.w; v[4]=y.x; v[5]=y.y; v[6]=y.z; v[7]=y.w;
  } else {
    #pragma unroll
    for (int j = 0; j < 8; ++j) v[j] = 0.f;
  }
  u16x8 o;
  #pragma unroll
  for (int j = 0; j < 8; ++j) o[j] = f2bf(v[j]);
  *(u16x8*)&dst[row * kk + k8] = o;
}

// ---------- gates pack: [Wih|Whh] concat-K, gate-interleaved rows ------------
// src row (per slot) r = g*512+j  ->  dst row = (j>>4)*64 + g*16 + (j&15)
__global__ void pack_gates(const float* __restrict__ Wih, int ka,
                           const float* __restrict__ Whh, int kb,
                           u16* __restrict__ dst, int kk) {
  int k8 = (blockIdx.x * 256 + threadIdx.x) * 8;
  if (k8 >= kk) return;
  long sr = blockIdx.y;               // s*2048 + r
  long s = sr >> 11;
  int  r = (int)(sr & 2047);
  int  g = r >> 9, j = r & 511;
  long drow = (s << 11) + ((j >> 4) * 64 + g * 16 + (j & 15));
  float v[8];
  if (k8 + 8 <= ka) {
    const float4* p = (const float4*)(Wih + sr * ka + k8);
    float4 x = p[0], y = p[1];
    v[0]=x.x; v[1]=x.y; v[2]=x.z; v[3]=x.w; v[4]=y.x; v[5]=y.y; v[6]=y.z; v[7]=y.w;
  } else {
    const float4* p = (const float4*)(Whh + sr * kb + (k8 - ka));
    float4 x = p[0], y = p[1];
    v[0]=x.x; v[1]=x.y; v[2]=x.z; v[3]=x.w; v[4]=y.x; v[5]=y.y; v[6]=y.z; v[7]=y.w;
  }
  u16x8 o;
  #pragma unroll
  for (int q = 0; q < 8; ++q) o[q] = f2bf(v[q]);
  *(u16x8*)&dst[drow * kk + k8] = o;
}

// ---------- highway/linear pack: [hw16|lin16] interleave ---------------------
// src row (per slot) j -> dst row = (j>>4)*32 + off16 + (j&15); K zero-pad past ks
__global__ void pack_hl(const float* __restrict__ src, int ks,
                        u16* __restrict__ dst, int kk, int off16) {
  int k8 = (blockIdx.x * 256 + threadIdx.x) * 8;
  if (k8 >= kk) return;
  long sj = blockIdx.y;               // s*512 + j
  long s = sj >> 9;
  int  j = (int)(sj & 511);
  long drow = (s << 10) + ((j >> 4) * 32 + off16 + (j & 15));
  float v[8];
  if (k8 + 8 <= ks) {
    const float4* p = (const float4*)(src + sj * ks + k8);
    float4 x = p[0], y = p[1];
    v[0]=x.x; v[1]=x.y; v[2]=x.z; v[3]=x.w; v[4]=y.x; v[5]=y.y; v[6]=y.z; v[7]=y.w;
  } else {
    #pragma unroll
    for (int q = 0; q < 8; ++q) v[q] = 0.f;
  }
  u16x8 o;
  #pragma unroll
  for (int q = 0; q < 8; ++q) o[q] = f2bf(v[q]);
  *(u16x8*)&dst[drow * kk + k8] = o;
}

__global__ void bias_sum(const float* __restrict__ a, const float* __restrict__ b,
                         float* __restrict__ o, int n) {
  int i = blockIdx.x * 256 + threadIdx.x;
  if (i < n) o[i] = a[i] + b[i];
}

__global__ void zero_f(float* __restrict__ p, int n) {
  for (int i = blockIdx.x * 256 + threadIdx.x; i < n; i += gridDim.x * 256) p[i] = 0.f;
}
__global__ void zero_u16k(u16* __restrict__ p, int n) {
  for (int i = blockIdx.x * 256 + threadIdx.x; i < n; i += gridDim.x * 256) p[i] = 0;
}

// ---------------- per-slot embedding gather into xcat[:,1024:1152] -----------
__global__ void gather_emb(const float* __restrict__ emb_s, const int* __restrict__ idx_s,
                           u16* __restrict__ xcat) {
  long b = blockIdx.x;
  int e = threadIdx.x;
  int ix = idx_s[b];
  xcat[b * KX0 + D_ + e] = f2bf(emb_s[(long)ix * E_ + e]);
}

// ---------------- fused bf16 MFMA GEMM + epilogue ----------------------------
// 128x128 tile, BK=32, 4 waves (2x2 of 64x64), 16x16x32 MFMA, global_load_lds.
// MODE 0: LSTM cell epilogue. Weights gate-interleaved so lane's acc[m][0..3]
//   = i,f,g,o for one j. Writes c (f32), h (bf16 into hdst), h (f32 into hf32).
// MODE 1: highway epilogue. Weights [hw16|lin16]-interleaved so acc[m][2p] /
//   acc[m][2p+1] = (hw, lin) for one j. Reads h0 from hf32, writes x1 bf16.
template<int MODE>
__global__ __launch_bounds__(256)
void gemm_fused(const u16* __restrict__ A, int lda,
                const u16* __restrict__ W, int ldw,
                int K, int ntn,
                const float* __restrict__ bsum,   // MODE0: [2048]; MODE1: hwb [512]
                float* __restrict__ cbuf,         // MODE0 only
                u16* __restrict__ hdst, int hld, int hoff,
                float* __restrict__ hf32) {       // MODE0: write; MODE1: read (h0)
  __shared__ __align__(16) u16 lA[128 * 32];
  __shared__ __align__(16) u16 lW[128 * 32];
  const int tid  = threadIdx.x;
  const int lane = tid & 63;
  const int wave = tid >> 6;
  const int tn = blockIdx.x % ntn;
  const int tm = blockIdx.x / ntn;
  const long row0 = (long)tm * 128;
  const long col0 = (long)tn * 128;
  const int wm = (wave >> 1) * 64;
  const int wn = (wave & 1) * 64;
  const int fr = lane & 15;
  const int fk = (lane >> 4) * 8;
  const int srow = lane >> 2;
  const int scol = (lane & 3) * 8;
  const int wr   = wave * 32;

  const u16* ga = A + (row0 + wr + srow) * lda + scol;
  const u16* gw = W + (col0 + wr + srow) * ldw + scol;
  u16* la0 = &lA[wr * 32];
  u16* lw0 = &lW[wr * 32];

  f32x4 acc[4][4] = {};

  for (int k0 = 0; k0 < K; k0 += 32) {
    __syncthreads();
    glds16(ga + k0,            la0);
    glds16(ga + k0 + 16 * lda, la0 + 16 * 32);
    glds16(gw + k0,            lw0);
    glds16(gw + k0 + 16 * ldw, lw0 + 16 * 32);
    __syncthreads();
    bf16x8 af[4], wf[4];
    #pragma unroll
    for (int m = 0; m < 4; ++m)
      af[m] = *(const bf16x8*)&lA[(wm + m * 16 + fr) * 32 + fk];
    #pragma unroll
    for (int n = 0; n < 4; ++n)
      wf[n] = *(const bf16x8*)&lW[(wn + n * 16 + fr) * 32 + fk];
    #pragma unroll
    for (int m = 0; m < 4; ++m)
      #pragma unroll
      for (int n = 0; n < 4; ++n)
        acc[m][n] = __builtin_amdgcn_mfma_f32_16x16x32_bf16(af[m], wf[n], acc[m][n], 0, 0, 0);
  }

  const int cr = (lane >> 4) * 4;
  const int jg = wn >> 6;   // 0 or 1

  if (MODE == 0) {
    const int j = tn * 32 + jg * 16 + fr;
    const float bi = bsum[j], bf = bsum[512 + j], bg = bsum[1024 + j], bo = bsum[1536 + j];
    #pragma unroll
    for (int m = 0; m < 4; ++m) {
      const long rbase = row0 + wm + m * 16 + cr;
      #pragma unroll
      for (int r = 0; r < 4; ++r) {
        const long ri = rbase + r;
        float gi = acc[m][0][r] + bi;
        float gf = acc[m][1][r] + bf;
        float gg = acc[m][2][r] + bg;
        float go = acc[m][3][r] + bo;
        float cv = cbuf[ri * H_ + j];
        float cn = sigmoidf_(gf) * cv + sigmoidf_(gi) * tanhf_(gg);
        float hn = sigmoidf_(go) * tanhf_(cn);
        cbuf[ri * H_ + j] = cn;
        hdst[ri * hld + hoff + j] = f2bf(hn);
        hf32[ri * H_ + j] = hn;
      }
    }
  } else {
    #pragma unroll
    for (int p = 0; p < 2; ++p) {
      const int j = tn * 64 + jg * 32 + p * 16 + fr;
      const float bj = bsum[j];
      #pragma unroll
      for (int m = 0; m < 4; ++m) {
        const long rbase = row0 + wm + m * 16 + cr;
        #pragma unroll
        for (int r = 0; r < 4; ++r) {
          const long ri = rbase + r;
          float gv = sigmoidf_(acc[m][2 * p][r] + bj);
          float x1 = gv * hf32[ri * H_ + j] + (1.f - gv) * acc[m][2 * p + 1][r];
          hdst[ri * hld + hoff + j] = f2bf(x1);
        }
      }
    }
  }
}

extern "C" void kernel_launch(void* const* d_in, const int* in_sizes, int n_in,
                              void* d_out, int out_size, void* d_ws, size_t ws_size,
                              hipStream_t stream) {
  const float* pred   = (const float*)d_in[0];
  const int*   labels = (const int*)d_in[1];
  const float* emb    = (const float*)d_in[2];
  const float* Wih0   = (const float*)d_in[3];
  const float* Whh0   = (const float*)d_in[4];
  const float* bih0   = (const float*)d_in[5];
  const float* bhh0   = (const float*)d_in[6];
  const float* hwW0   = (const float*)d_in[7];
  const float* hwb0   = (const float*)d_in[8];
  const float* linW0  = (const float*)d_in[9];
  const float* Wih1   = (const float*)d_in[10];
  const float* Whh1   = (const float*)d_in[11];
  const float* bih1   = (const float*)d_in[12];
  const float* bhh1   = (const float*)d_in[13];
  float* out = (float*)d_out;

  char* ws = (char*)d_ws;
  size_t off = 0;
  auto alloc = [&](size_t bytes) {
    char* p = ws + off;
    off = (off + bytes + 255) & ~(size_t)255;
    return p;
  };
  u16* WC0   = (u16*)alloc((size_t)S_ * G4H * KX0 * 2);   // gate-interleaved [Wih0|Whh0]
  u16* WHL   = (u16*)alloc((size_t)S_ * 1024 * KX0 * 2);  // [hw16|lin16] interleave
  u16* WC1   = (u16*)alloc((size_t)S_ * G4H * KX1 * 2);   // gate-interleaved [Wih1|Whh1]
  u16* xcat  = (u16*)alloc((size_t)B_ * KX0 * 2);         // [pred|emb|h0] bf16
  u16* x1cat = (u16*)alloc((size_t)B_ * KX1 * 2);         // [x1|h1] bf16
  float* c0   = (float*)alloc((size_t)B_ * H_ * 4);
  float* c1   = (float*)alloc((size_t)B_ * H_ * 4);
  float* h0f  = (float*)alloc((size_t)B_ * H_ * 4);
  float* bs0  = (float*)alloc((size_t)S_ * G4H * 4);      // bih0+bhh0
  float* bs1  = (float*)alloc((size_t)S_ * G4H * 4);      // bih1+bhh1

  // -------- phase A: weight conversion + state init ---------------------------
  pack_gates<<<dim3(1, S_ * G4H), 256, 0, stream>>>(Wih0, D0_, Whh0, H_, WC0, KX0);
  pack_gates<<<dim3(1, S_ * G4H), 256, 0, stream>>>(Wih1, H_, Whh1, H_, WC1, KX1);
  pack_hl<<<dim3(1, S_ * H_), 256, 0, stream>>>(hwW0, KX0, WHL, KX0, 0);
  pack_hl<<<dim3(1, S_ * H_), 256, 0, stream>>>(linW0, D0_, WHL, KX0, 16);
  pack8<<<dim3(1, B_), 256, 0, stream>>>(pred, D_, xcat, KX0);
  bias_sum<<<(S_ * G4H + 255) / 256, 256, 0, stream>>>(bih0, bhh0, bs0, S_ * G4H);
  bias_sum<<<(S_ * G4H + 255) / 256, 256, 0, stream>>>(bih1, bhh1, bs1, S_ * G4H);
  zero_f<<<256, 256, 0, stream>>>(c0, B_ * H_);
  zero_f<<<256, 256, 0, stream>>>(c1, B_ * H_);
  zero_u16k<<<256, 256, 0, stream>>>(x1cat, B_ * KX1);

  // -------- sequential slot loop ----------------------------------------------
  for (int s = 0; s < S_; ++s) {
    gather_emb<<<B_, E_, 0, stream>>>(emb + (size_t)s * V_ * E_, labels + (size_t)s * B_, xcat);

    // layer-0 gates + cell (fused): [x|h0] @ WC0^T, M=4096,N=2048,K=1664
    gemm_fused<0><<<(B_ / 128) * (G4H / 128), 256, 0, stream>>>(
        xcat, KX0, WC0 + (size_t)s * G4H * KX0, KX0, KX0, G4H / 128,
        bs0 + (size_t)s * G4H, c0, xcat, KX0, D0_, h0f);

    // merged highway+linear + combine (fused): N=1024,K=1664
    gemm_fused<1><<<(B_ / 128) * (1024 / 128), 256, 0, stream>>>(
        xcat, KX0, WHL + (size_t)s * 1024 * KX0, KX0, KX0, 1024 / 128,
        hwb0 + (size_t)s * H_, nullptr, x1cat, KX1, 0, h0f);

    // layer-1 gates + cell (fused): [x1|h1] @ WC1^T, N=2048,K=1024
    gemm_fused<0><<<(B_ / 128) * (G4H / 128), 256, 0, stream>>>(
        x1cat, KX1, WC1 + (size_t)s * G4H * KX1, KX1, KX1, G4H / 128,
        bs1 + (size_t)s * G4H, c1, x1cat, KX1, H_, out);
  }
}

// Round 4
// 680.985 us; speedup vs baseline: 2.1358x; 1.5362x over previous
//
#include <hip/hip_runtime.h>
#include <stdint.h>

typedef unsigned short u16;

#define S_   7
#define B_   4096
#define D_   1024
#define E_   128
#define H_   512
#define V_   200
#define D0_  1152   // D+E
#define KX0  1664   // D0+H  (xcat width: [x | h0])
#define KX1  1024   // 2H    (x1cat width: [x1 | h1])
#define G4H  2048   // 4H

typedef __bf16 bf16x8 __attribute__((ext_vector_type(8)));
typedef float  f32x4  __attribute__((ext_vector_type(4)));
typedef u16    u16x8  __attribute__((ext_vector_type(8)));

__device__ __forceinline__ u16 f2bf(float f) {
  union { float f; uint32_t u; } v; v.f = f;
  uint32_t r = v.u + 0x7fffu + ((v.u >> 16) & 1u);   // RNE
  return (u16)(r >> 16);
}
__device__ __forceinline__ float bf2f(u16 b) {
  union { uint32_t u; float f; } v; v.u = ((uint32_t)b) << 16;
  return v.f;
}
__device__ __forceinline__ float sigmoidf_(float x) { return 1.0f / (1.0f + __expf(-x)); }
__device__ __forceinline__ float tanhf_(float x) {
  float t = __expf(-2.f * fabsf(x));
  return copysignf((1.f - t) / (1.f + t), x);
}

__device__ __forceinline__ void glds16(const u16* g, u16* l) {
  __builtin_amdgcn_global_load_lds(
      (const __attribute__((address_space(1))) uint32_t*)g,
      (__attribute__((address_space(3))) uint32_t*)l, 16, 0, 0);
}

// ---------- vectorized f32->bf16 pack (identity rows, zero pad past ka) ------
__global__ void pack8(const float* __restrict__ A, int ka,
                      u16* __restrict__ dst, int kk) {
  int k8 = (blockIdx.x * 256 + threadIdx.x) * 8;
  long row = blockIdx.y;
  if (k8 >= kk) return;
  float v[8];
  if (k8 + 8 <= ka) {
    const float4* p = (const float4*)(A + row * ka + k8);
    float4 x = p[0], y = p[1];
    v[0]=x.x; v[1]=x.y; v[2]=x.z; v[3]=x.w; v[4]=y.x; v[5]=y.y; v[6]=y.z; v[7]=y.w;
  } else {
    #pragma unroll
    for (int j = 0; j < 8; ++j) v[j] = 0.f;
  }
  u16x8 o;
  #pragma unroll
  for (int j = 0; j < 8; ++j) o[j] = f2bf(v[j]);
  *(u16x8*)&dst[row * kk + k8] = o;
}

// ---------- gates pack: [Wih|Whh] concat-K, gate-interleaved rows ------------
// src row (per slot) r = g*512+j  ->  dst row = (j>>4)*64 + g*16 + (j&15)
__global__ void pack_gates(const float* __restrict__ Wih, int ka,
                           const float* __restrict__ Whh, int kb,
                           u16* __restrict__ dst, int kk) {
  int k8 = (blockIdx.x * 256 + threadIdx.x) * 8;
  if (k8 >= kk) return;
  long sr = blockIdx.y;               // s*2048 + r
  long s = sr >> 11;
  int  r = (int)(sr & 2047);
  int  g = r >> 9, j = r & 511;
  long drow = (s << 11) + ((j >> 4) * 64 + g * 16 + (j & 15));
  float v[8];
  if (k8 + 8 <= ka) {
    const float4* p = (const float4*)(Wih + sr * ka + k8);
    float4 x = p[0], y = p[1];
    v[0]=x.x; v[1]=x.y; v[2]=x.z; v[3]=x.w; v[4]=y.x; v[5]=y.y; v[6]=y.z; v[7]=y.w;
  } else {
    const float4* p = (const float4*)(Whh + sr * kb + (k8 - ka));
    float4 x = p[0], y = p[1];
    v[0]=x.x; v[1]=x.y; v[2]=x.z; v[3]=x.w; v[4]=y.x; v[5]=y.y; v[6]=y.z; v[7]=y.w;
  }
  u16x8 o;
  #pragma unroll
  for (int q = 0; q < 8; ++q) o[q] = f2bf(v[q]);
  *(u16x8*)&dst[drow * kk + k8] = o;
}

// ---------- highway/linear pack: [hw16|lin16] interleave ---------------------
__global__ void pack_hl(const float* __restrict__ src, int ks,
                        u16* __restrict__ dst, int kk, int off16) {
  int k8 = (blockIdx.x * 256 + threadIdx.x) * 8;
  if (k8 >= kk) return;
  long sj = blockIdx.y;               // s*512 + j
  long s = sj >> 9;
  int  j = (int)(sj & 511);
  long drow = (s << 10) + ((j >> 4) * 32 + off16 + (j & 15));
  float v[8];
  if (k8 + 8 <= ks) {
    const float4* p = (const float4*)(src + sj * ks + k8);
    float4 x = p[0], y = p[1];
    v[0]=x.x; v[1]=x.y; v[2]=x.z; v[3]=x.w; v[4]=y.x; v[5]=y.y; v[6]=y.z; v[7]=y.w;
  } else {
    #pragma unroll
    for (int q = 0; q < 8; ++q) v[q] = 0.f;
  }
  u16x8 o;
  #pragma unroll
  for (int q = 0; q < 8; ++q) o[q] = f2bf(v[q]);
  *(u16x8*)&dst[drow * kk + k8] = o;
}

__global__ void bias_sum(const float* __restrict__ a, const float* __restrict__ b,
                         float* __restrict__ o, int n) {
  int i = blockIdx.x * 256 + threadIdx.x;
  if (i < n) o[i] = a[i] + b[i];
}

__global__ void zero_f(float* __restrict__ p, int n) {
  for (int i = blockIdx.x * 256 + threadIdx.x; i < n; i += gridDim.x * 256) p[i] = 0.f;
}
__global__ void zero_u16k(u16* __restrict__ p, int n) {
  for (int i = blockIdx.x * 256 + threadIdx.x; i < n; i += gridDim.x * 256) p[i] = 0;
}

// ---------------- per-slot embedding gather into xcat[:,1024:1152] -----------
__global__ void gather_emb(const float* __restrict__ emb_s, const int* __restrict__ idx_s,
                           u16* __restrict__ xcat) {
  long b = blockIdx.x;
  int e = threadIdx.x;
  int ix = idx_s[b];
  xcat[b * KX0 + D_ + e] = f2bf(emb_s[(long)ix * E_ + e]);
}

// ---------------- fused bf16 MFMA GEMM + epilogue ----------------------------
// 128x128 tile, BK=64, double-buffered LDS, prefetch-before-compute (T3-min),
// XOR-swizzled staging (linear gload_lds dest + swizzled source + swizzled read),
// XCD-chunked blockIdx. 4 waves (2x2 of 64x64), 16x16x32 MFMA.
// MODE 0: LSTM cell epilogue (gate-interleaved weights; acc[m][0..3]=i,f,g,o).
// MODE 1: highway epilogue ([hw16|lin16] weights; reads h0 bf16 from xcat).
template<int MODE>
__global__ __launch_bounds__(256)
void gemm_fused(const u16* __restrict__ A, int lda,
                const u16* __restrict__ W, int ldw,
                int K, int ntn, int cpx,
                const float* __restrict__ bsum,   // MODE0: [2048]; MODE1: hwb [512]
                float* __restrict__ cbuf,         // MODE0 only
                u16* __restrict__ hdst, int hld, int hoff,
                float* __restrict__ hf32,         // MODE0 optional f32 h out (or null)
                const u16* __restrict__ xcat0) {  // MODE1: h0 bf16 source
  __shared__ __align__(16) u16 lds[2 * 2 * 128 * 64];   // [buf][A|W][128][64], 64 KiB
  const int BUFSZ = 2 * 128 * 64;
  const int tid  = threadIdx.x;
  const int lane = tid & 63;
  const int wave = tid >> 6;
  const int p    = blockIdx.x;
  const int bid  = (p & 7) * cpx + (p >> 3);     // XCD-chunked remap (grid%8==0)
  const int tn = bid % ntn;
  const int tm = bid / ntn;
  const long row0 = (long)tm * 128;
  const long col0 = (long)tn * 128;
  const int wm = (wave >> 1) * 64;
  const int wn = (wave & 1) * 64;
  const int fr = lane & 15;
  const int fk = (lane >> 4) * 8;
  const int wr = wave * 32;

  // staging: wave covers rows [wr, wr+32), 4 issues of 8 rows; source col
  // pre-swizzled so linear LDS dest + XOR'd read return the right element.
  const int srow = wr + (lane >> 3);
  const int scol = ((lane & 7) ^ ((lane >> 3) & 7)) * 8;
  const u16* ga = A + (row0 + srow) * (long)lda + scol;
  const u16* gw = W + (col0 + srow) * (long)ldw + scol;
  u16* dstA = &lds[0] + wr * 64 + lane * 8;
  u16* dstW = dstA + 128 * 64;

  // fragment read offsets (elements), XOR-swizzled within the 64-col row
  int aoff[4], woff[4];
  #pragma unroll
  for (int m = 0; m < 4; ++m) aoff[m] = (wm + m * 16 + fr) * 64;
  #pragma unroll
  for (int n = 0; n < 4; ++n) woff[n] = (wn + n * 16 + fr) * 64 + 128 * 64;
  const int swz = (fr & 7) << 3;
  const int kk0 = (0 + fk) ^ swz;
  const int kk1 = (32 + fk) ^ swz;

  f32x4 acc[4][4] = {};
  const int nt = K >> 6;

  // prologue: stage tile 0 into buf 0
  #pragma unroll
  for (int i = 0; i < 4; ++i) {
    glds16(ga + (long)(i * 8) * lda, dstA + i * 512);
    glds16(gw + (long)(i * 8) * ldw, dstW + i * 512);
  }

  int cur = 0;
  for (int t = 0; t < nt; ++t) {
    __syncthreads();                  // implicit vmcnt(0): tile t ready in buf[cur]
    if (t + 1 < nt) {                 // prefetch tile t+1 into the other buffer
      const long k0 = (long)(t + 1) << 6;
      const int nb = (cur ^ 1) * BUFSZ;
      #pragma unroll
      for (int i = 0; i < 4; ++i) {
        glds16(ga + (long)(i * 8) * lda + k0, dstA + nb + i * 512);
        glds16(gw + (long)(i * 8) * ldw + k0, dstW + nb + i * 512);
      }
    }
    const u16* base = &lds[cur * BUFSZ];
    bf16x8 af0[4], wf0[4], af1[4], wf1[4];
    #pragma unroll
    for (int m = 0; m < 4; ++m) af0[m] = *(const bf16x8*)&base[aoff[m] + kk0];
    #pragma unroll
    for (int n = 0; n < 4; ++n) wf0[n] = *(const bf16x8*)&base[woff[n] + kk0];
    #pragma unroll
    for (int m = 0; m < 4; ++m) af1[m] = *(const bf16x8*)&base[aoff[m] + kk1];
    #pragma unroll
    for (int n = 0; n < 4; ++n) wf1[n] = *(const bf16x8*)&base[woff[n] + kk1];
    #pragma unroll
    for (int m = 0; m < 4; ++m)
      #pragma unroll
      for (int n = 0; n < 4; ++n)
        acc[m][n] = __builtin_amdgcn_mfma_f32_16x16x32_bf16(af0[m], wf0[n], acc[m][n], 0, 0, 0);
    #pragma unroll
    for (int m = 0; m < 4; ++m)
      #pragma unroll
      for (int n = 0; n < 4; ++n)
        acc[m][n] = __builtin_amdgcn_mfma_f32_16x16x32_bf16(af1[m], wf1[n], acc[m][n], 0, 0, 0);
    cur ^= 1;
  }

  const int cr = (lane >> 4) * 4;
  const int jg = wn >> 6;   // 0 or 1

  if (MODE == 0) {
    const int j = tn * 32 + jg * 16 + fr;
    const float bi = bsum[j], bf = bsum[512 + j], bg = bsum[1024 + j], bo = bsum[1536 + j];
    #pragma unroll
    for (int m = 0; m < 4; ++m) {
      const long rbase = row0 + wm + m * 16 + cr;
      #pragma unroll
      for (int r = 0; r < 4; ++r) {
        const long ri = rbase + r;
        float gi = acc[m][0][r] + bi;
        float gf = acc[m][1][r] + bf;
        float gg = acc[m][2][r] + bg;
        float go = acc[m][3][r] + bo;
        float cv = cbuf[ri * H_ + j];
        float cn = sigmoidf_(gf) * cv + sigmoidf_(gi) * tanhf_(gg);
        float hn = sigmoidf_(go) * tanhf_(cn);
        cbuf[ri * H_ + j] = cn;
        hdst[ri * hld + hoff + j] = f2bf(hn);
        if (hf32) hf32[ri * H_ + j] = hn;
      }
    }
  } else {
    #pragma unroll
    for (int pp = 0; pp < 2; ++pp) {
      const int j = tn * 64 + jg * 32 + pp * 16 + fr;
      const float bj = bsum[j];
      #pragma unroll
      for (int m = 0; m < 4; ++m) {
        const long rbase = row0 + wm + m * 16 + cr;
        #pragma unroll
        for (int r = 0; r < 4; ++r) {
          const long ri = rbase + r;
          float gv = sigmoidf_(acc[m][2 * pp][r] + bj);
          float h0 = bf2f(xcat0[ri * KX0 + D0_ + j]);
          float x1 = gv * h0 + (1.f - gv) * acc[m][2 * pp + 1][r];
          hdst[ri * hld + hoff + j] = f2bf(x1);
        }
      }
    }
  }
}

extern "C" void kernel_launch(void* const* d_in, const int* in_sizes, int n_in,
                              void* d_out, int out_size, void* d_ws, size_t ws_size,
                              hipStream_t stream) {
  const float* pred   = (const float*)d_in[0];
  const int*   labels = (const int*)d_in[1];
  const float* emb    = (const float*)d_in[2];
  const float* Wih0   = (const float*)d_in[3];
  const float* Whh0   = (const float*)d_in[4];
  const float* bih0   = (const float*)d_in[5];
  const float* bhh0   = (const float*)d_in[6];
  const float* hwW0   = (const float*)d_in[7];
  const float* hwb0   = (const float*)d_in[8];
  const float* linW0  = (const float*)d_in[9];
  const float* Wih1   = (const float*)d_in[10];
  const float* Whh1   = (const float*)d_in[11];
  const float* bih1   = (const float*)d_in[12];
  const float* bhh1   = (const float*)d_in[13];
  float* out = (float*)d_out;

  char* ws = (char*)d_ws;
  size_t off = 0;
  auto alloc = [&](size_t bytes) {
    char* p = ws + off;
    off = (off + bytes + 255) & ~(size_t)255;
    return p;
  };
  u16* WC0   = (u16*)alloc((size_t)S_ * G4H * KX0 * 2);   // gate-interleaved [Wih0|Whh0]
  u16* WHL   = (u16*)alloc((size_t)S_ * 1024 * KX0 * 2);  // [hw16|lin16] interleave
  u16* WC1   = (u16*)alloc((size_t)S_ * G4H * KX1 * 2);   // gate-interleaved [Wih1|Whh1]
  u16* xcat  = (u16*)alloc((size_t)B_ * KX0 * 2);         // [pred|emb|h0] bf16
  u16* x1cat = (u16*)alloc((size_t)B_ * KX1 * 2);         // [x1|h1] bf16
  float* c0   = (float*)alloc((size_t)B_ * H_ * 4);
  float* c1   = (float*)alloc((size_t)B_ * H_ * 4);
  float* bs0  = (float*)alloc((size_t)S_ * G4H * 4);      // bih0+bhh0
  float* bs1  = (float*)alloc((size_t)S_ * G4H * 4);      // bih1+bhh1

  // -------- phase A: weight conversion + state init ---------------------------
  pack_gates<<<dim3(1, S_ * G4H), 256, 0, stream>>>(Wih0, D0_, Whh0, H_, WC0, KX0);
  pack_gates<<<dim3(1, S_ * G4H), 256, 0, stream>>>(Wih1, H_, Whh1, H_, WC1, KX1);
  pack_hl<<<dim3(1, S_ * H_), 256, 0, stream>>>(hwW0, KX0, WHL, KX0, 0);
  pack_hl<<<dim3(1, S_ * H_), 256, 0, stream>>>(linW0, D0_, WHL, KX0, 16);
  pack8<<<dim3(1, B_), 256, 0, stream>>>(pred, D_, xcat, KX0);
  bias_sum<<<(S_ * G4H + 255) / 256, 256, 0, stream>>>(bih0, bhh0, bs0, S_ * G4H);
  bias_sum<<<(S_ * G4H + 255) / 256, 256, 0, stream>>>(bih1, bhh1, bs1, S_ * G4H);
  zero_f<<<256, 256, 0, stream>>>(c0, B_ * H_);
  zero_f<<<256, 256, 0, stream>>>(c1, B_ * H_);
  zero_u16k<<<256, 256, 0, stream>>>(x1cat, B_ * KX1);

  const int g0 = (B_ / 128) * (G4H / 128);    // 512 blocks
  const int g1 = (B_ / 128) * (1024 / 128);   // 256 blocks

  // -------- sequential slot loop ----------------------------------------------
  for (int s = 0; s < S_; ++s) {
    gather_emb<<<B_, E_, 0, stream>>>(emb + (size_t)s * V_ * E_, labels + (size_t)s * B_, xcat);

    // layer-0 gates + cell (fused): [x|h0] @ WC0^T, M=4096,N=2048,K=1664
    gemm_fused<0><<<g0, 256, 0, stream>>>(
        xcat, KX0, WC0 + (size_t)s * G4H * KX0, KX0, KX0, G4H / 128, g0 / 8,
        bs0 + (size_t)s * G4H, c0, xcat, KX0, D0_, nullptr, nullptr);

    // merged highway+linear + combine (fused): N=1024,K=1664
    gemm_fused<1><<<g1, 256, 0, stream>>>(
        xcat, KX0, WHL + (size_t)s * 1024 * KX0, KX0, KX0, 1024 / 128, g1 / 8,
        hwb0 + (size_t)s * H_, nullptr, x1cat, KX1, 0, nullptr, xcat);

    // layer-1 gates + cell (fused): [x1|h1] @ WC1^T, N=2048,K=1024
    gemm_fused<0><<<g0, 256, 0, stream>>>(
        x1cat, KX1, WC1 + (size_t)s * G4H * KX1, KX1, KX1, G4H / 128, g0 / 8,
        bs1 + (size_t)s * G4H, c1, x1cat, KX1, H_, out, nullptr);
  }
}